// Round 1
// baseline (11173.347 us; speedup 1.0000x reference)
//
#include <hip/hip_runtime.h>
#include <math.h>

// ---------------- problem constants ----------------
#define C_    256
#define NH_   8
#define HD_   32
#define N_    64      // tokens per window (8x8)
#define NTOK  65536   // B * 64 * 64
#define MLPH  1024
#define CPBH  512

// LDS sizes (bytes)
#define ATTN_LDS ((64*256 + 3*64*36 + 64*65) * 4)   // 109,824
#define MLP_LDS  ((16*256 + 16*1024) * 4)           // 81,920

// ---------------- init copy ----------------
__global__ void copy_kernel(float* __restrict__ dst, const float* __restrict__ src) {
    size_t i = (size_t)blockIdx.x * blockDim.x + threadIdx.x;
    reinterpret_cast<float4*>(dst)[i] = reinterpret_cast<const float4*>(src)[i];
}

// ---------------- continuous position bias table ----------------
// biastab[e][h] = 16*sigmoid( relu(tab(e) @ w1^T + b1) @ w2^T )[h],  e in [0,225)
__global__ void cpb_kernel(const float* __restrict__ w1, const float* __restrict__ b1,
                           const float* __restrict__ w2, float* __restrict__ biastab) {
    __shared__ float red[256];
    const int e = blockIdx.x;
    const int t = threadIdx.x;
    const int p = e / 15, q = e % 15;
    const float v0 = (float)(p - 7) * (8.0f / 7.0f);
    const float v1 = (float)(q - 7) * (8.0f / 7.0f);
    const float t0 = copysignf(log2f(fabsf(v0) + 1.0f) * (1.0f / 3.0f), v0);
    const float t1 = copysignf(log2f(fabsf(v1) + 1.0f) * (1.0f / 3.0f), v1);
    const float ha = fmaxf(0.0f, t0 * w1[t * 2]         + t1 * w1[t * 2 + 1]         + b1[t]);
    const float hb = fmaxf(0.0f, t0 * w1[(t + 256) * 2] + t1 * w1[(t + 256) * 2 + 1] + b1[t + 256]);
    for (int h = 0; h < 8; ++h) {
        __syncthreads();
        red[t] = ha * w2[h * 512 + t] + hb * w2[h * 512 + t + 256];
        __syncthreads();
        for (int s = 128; s > 0; s >>= 1) {
            if (t < s) red[t] += red[t + s];
            __syncthreads();
        }
        if (t == 0) biastab[e * 8 + h] = 16.0f / (1.0f + expf(-red[0]));
    }
}

// ---------------- fused window attention (qkv + cosine attn + softmax + PV) ----------------
// one block per window; writes attn_out[(win*64+n)*256 + h*32 + d]
__global__ __launch_bounds__(256) void attn_kernel(
    const float* __restrict__ x, const float* __restrict__ qw,
    const float* __restrict__ qb, const float* __restrict__ lsc,
    const float* __restrict__ biastab, float* __restrict__ ao, int shift)
{
    extern __shared__ float lds[];
    float* xs = lds;                  // [64][256]
    float* qs = lds + 64 * 256;       // [64][36]
    float* ks = qs + 64 * 36;         // [64][36]
    float* vs = ks + 64 * 36;         // [64][36]
    float* sc = vs + 64 * 36;         // [64][65]

    const int t   = threadIdx.x;
    const int win = blockIdx.x;
    const int b = win >> 6, wh = (win >> 3) & 7, ww = win & 7;

    // ---- stage window tokens into LDS (with roll-by-(-shift) mapping) ----
    {
        int n = t >> 2, qt = t & 3;
        int i = n >> 3, j = n & 7;
        int r = (wh * 8 + i + shift) & 63;
        int c = (ww * 8 + j + shift) & 63;
        const float4* src = reinterpret_cast<const float4*>(
            x + ((size_t)(b * 4096 + r * 64 + c)) * 256) + qt * 16;
        float4* dst = reinterpret_cast<float4*>(xs + n * 256) + qt * 16;
        #pragma unroll
        for (int k2 = 0; k2 < 16; ++k2) dst[k2] = src[k2];
    }
    __syncthreads();

    const int d = t & 31, ng = t >> 5;       // qkv phase mapping
    const int nq = t >> 2, quad = t & 3;     // logits/PV phase mapping
    const int i1 = nq >> 3, j1 = nq & 7;

    for (int h = 0; h < 8; ++h) {
        // ---- qkv: thread computes q/k/v[d] for 8 tokens ----
        float aq[8], ak[8], av[8];
        #pragma unroll
        for (int u = 0; u < 8; ++u) { aq[u] = 0.f; ak[u] = 0.f; av[u] = 0.f; }
        const float4* wq = reinterpret_cast<const float4*>(qw + (size_t)(h * 32 + d) * 256);
        const float4* wk = reinterpret_cast<const float4*>(qw + (size_t)(256 + h * 32 + d) * 256);
        const float4* wv = reinterpret_cast<const float4*>(qw + (size_t)(512 + h * 32 + d) * 256);
        for (int c4 = 0; c4 < 64; ++c4) {
            float4 q4 = wq[c4], k4 = wk[c4], v4 = wv[c4];
            #pragma unroll
            for (int u = 0; u < 8; ++u) {
                float4 xv = reinterpret_cast<const float4*>(xs + (ng * 8 + u) * 256)[c4];
                aq[u] += xv.x * q4.x + xv.y * q4.y + xv.z * q4.z + xv.w * q4.w;
                ak[u] += xv.x * k4.x + xv.y * k4.y + xv.z * k4.z + xv.w * k4.w;
                av[u] += xv.x * v4.x + xv.y * v4.y + xv.z * v4.z + xv.w * v4.w;
            }
        }
        const float bq = qb[h * 32 + d], bk = qb[256 + h * 32 + d], bv = qb[512 + h * 32 + d];
        #pragma unroll
        for (int u = 0; u < 8; ++u) {
            int n = ng * 8 + u;
            qs[n * 36 + d] = aq[u] + bq;
            ks[n * 36 + d] = ak[u] + bk;
            vs[n * 36 + d] = av[u] + bv;
        }
        __syncthreads();

        // ---- L2-normalize q and k rows (cosine attention) ----
        if (t < 128) {
            float* pp = (t < 64) ? qs : ks;
            int n = t & 63;
            float s = 0.f;
            #pragma unroll
            for (int k4 = 0; k4 < 8; ++k4) {
                float4 v4 = reinterpret_cast<float4*>(pp + n * 36)[k4];
                s += v4.x * v4.x + v4.y * v4.y + v4.z * v4.z + v4.w * v4.w;
            }
            float inv = 1.0f / (sqrtf(s) + 1e-12f);
            #pragma unroll
            for (int k4 = 0; k4 < 8; ++k4) {
                float4 v4 = reinterpret_cast<float4*>(pp + n * 36)[k4];
                v4.x *= inv; v4.y *= inv; v4.z *= inv; v4.w *= inv;
                reinterpret_cast<float4*>(pp + n * 36)[k4] = v4;
            }
        }
        __syncthreads();

        // ---- logits: thread computes 16 entries of row nq ----
        {
            const float scale = expf(fminf(lsc[h], 4.6051702f)); // min(logit_scale, ln 100)
            int reg_n = 0;
            if (shift) {
                int pr = wh * 8 + i1, pc = ww * 8 + j1;
                reg_n = ((pr < 56) ? 0 : ((pr < 60) ? 1 : 2)) * 3 +
                        ((pc < 56) ? 0 : ((pc < 60) ? 1 : 2));
            }
            const int m0 = quad * 16;
            for (int m = m0; m < m0 + 16; ++m) {
                float dot = 0.f;
                #pragma unroll
                for (int k4 = 0; k4 < 8; ++k4) {
                    float4 qv = reinterpret_cast<const float4*>(qs + nq * 36)[k4];
                    float4 kv = reinterpret_cast<const float4*>(ks + m * 36)[k4];
                    dot += qv.x * kv.x + qv.y * kv.y + qv.z * kv.z + qv.w * kv.w;
                }
                float lg = dot * scale;
                int i2 = m >> 3, j2 = m & 7;
                lg += biastab[((i1 - i2 + 7) * 15 + (j1 - j2 + 7)) * 8 + h];
                if (shift) {
                    int pr = wh * 8 + i2, pc = ww * 8 + j2;
                    int reg_m = ((pr < 56) ? 0 : ((pr < 60) ? 1 : 2)) * 3 +
                                ((pc < 56) ? 0 : ((pc < 60) ? 1 : 2));
                    if (reg_m != reg_n) lg -= 100.f;
                }
                sc[nq * 65 + m] = lg;
            }
        }
        __syncthreads();

        // ---- softmax per row ----
        if (t < 64) {
            float mx = -1e30f;
            for (int m = 0; m < 64; ++m) mx = fmaxf(mx, sc[t * 65 + m]);
            float s = 0.f;
            for (int m = 0; m < 64; ++m) { float e = expf(sc[t * 65 + m] - mx); sc[t * 65 + m] = e; s += e; }
            float inv = 1.0f / s;
            for (int m = 0; m < 64; ++m) sc[t * 65 + m] *= inv;
        }
        __syncthreads();

        // ---- PV: thread computes 8 output dims of row nq ----
        {
            const int d0 = quad * 8;
            float o[8];
            #pragma unroll
            for (int u = 0; u < 8; ++u) o[u] = 0.f;
            for (int m = 0; m < 64; ++m) {
                float p = sc[nq * 65 + m];
                float4 v0 = *reinterpret_cast<const float4*>(vs + m * 36 + d0);
                float4 v1 = *reinterpret_cast<const float4*>(vs + m * 36 + d0 + 4);
                o[0] += p * v0.x; o[1] += p * v0.y; o[2] += p * v0.z; o[3] += p * v0.w;
                o[4] += p * v1.x; o[5] += p * v1.y; o[6] += p * v1.z; o[7] += p * v1.w;
            }
            float* dst = ao + ((size_t)(win * 64 + nq)) * 256 + h * 32 + d0;
            *reinterpret_cast<float4*>(dst)     = make_float4(o[0], o[1], o[2], o[3]);
            *reinterpret_cast<float4*>(dst + 4) = make_float4(o[4], o[5], o[6], o[7]);
        }
        __syncthreads();
    }
}

// ---------------- proj + bias + post-LN + un-partition/un-roll + residual ----------------
// 8 tokens per block; wave w handles local tokens 2w, 2w+1; lane l handles channels l+64r
__global__ __launch_bounds__(256) void proj_kernel(
    const float* __restrict__ ao_g, const float* __restrict__ pw,
    const float* __restrict__ pb, const float* __restrict__ n1s,
    const float* __restrict__ n1b, float* __restrict__ x, int shift)
{
    __shared__ float ao[8][256];
    const int t = threadIdx.x;
    const size_t tok0 = (size_t)blockIdx.x * 8;

    {   // stage 8 input rows
        int tk = t >> 5, pos = (t & 31) * 8;
        const float4* src = reinterpret_cast<const float4*>(ao_g + (tok0 + tk) * 256 + pos);
        *reinterpret_cast<float4*>(&ao[tk][pos])     = src[0];
        *reinterpret_cast<float4*>(&ao[tk][pos + 4]) = src[1];
    }
    __syncthreads();

    const int wid = t >> 6, l = t & 63;
    float acc[2][4];
    #pragma unroll
    for (int a = 0; a < 2; ++a)
        #pragma unroll
        for (int r = 0; r < 4; ++r) acc[a][r] = 0.f;

    for (int c = 0; c < 256; c += 4) {
        float4 xa = *reinterpret_cast<const float4*>(&ao[wid * 2][c]);
        float4 xb = *reinterpret_cast<const float4*>(&ao[wid * 2 + 1][c]);
        #pragma unroll
        for (int r = 0; r < 4; ++r) {
            float4 wv = *reinterpret_cast<const float4*>(pw + (size_t)(l + 64 * r) * 256 + c);
            acc[0][r] += xa.x * wv.x + xa.y * wv.y + xa.z * wv.z + xa.w * wv.w;
            acc[1][r] += xb.x * wv.x + xb.y * wv.y + xb.z * wv.z + xb.w * wv.w;
        }
    }

    #pragma unroll
    for (int a = 0; a < 2; ++a) {
        float v[4], s = 0.f, ss = 0.f;
        #pragma unroll
        for (int r = 0; r < 4; ++r) {
            v[r] = acc[a][r] + pb[l + 64 * r];
            s += v[r]; ss += v[r] * v[r];
        }
        for (int m = 1; m < 64; m <<= 1) { s += __shfl_xor(s, m); ss += __shfl_xor(ss, m); }
        float mean = s * (1.0f / 256.0f);
        float var  = ss * (1.0f / 256.0f) - mean * mean;
        float rs   = rsqrtf(var + 1e-5f);

        size_t gt = tok0 + wid * 2 + a;
        int win = (int)(gt >> 6), n = (int)(gt & 63);
        int b = win >> 6, wh = (win >> 3) & 7, ww = win & 7, i = n >> 3, j = n & 7;
        int pr = (wh * 8 + i + shift) & 63;
        int pc = (ww * 8 + j + shift) & 63;
        float* xp = x + ((size_t)(b * 4096 + pr * 64 + pc)) * 256;
        #pragma unroll
        for (int r = 0; r < 4; ++r) {
            int oc = l + 64 * r;
            xp[oc] += (v[r] - mean) * rs * n1s[oc] + n1b[oc];
        }
    }
}

// ---------------- fused MLP (256 -> 1024 gelu -> 256) + post-LN + residual ----------------
// 16 tokens per block
__global__ __launch_bounds__(256) void mlp_kernel(
    float* __restrict__ x, const float* __restrict__ w1, const float* __restrict__ b1,
    const float* __restrict__ w2, const float* __restrict__ b2,
    const float* __restrict__ n2s, const float* __restrict__ n2b)
{
    extern __shared__ float lds[];
    float* xr  = lds;             // [16][256]
    float* hid = lds + 16 * 256;  // [16][1024]
    const int t = threadIdx.x;
    const size_t tok0 = (size_t)blockIdx.x * 16;

    {   // stage 16 x rows
        const float4* src = reinterpret_cast<const float4*>(x + tok0 * 256);
        float4* dst = reinterpret_cast<float4*>(xr);
        #pragma unroll
        for (int k = 0; k < 4; ++k) dst[t + 256 * k] = src[t + 256 * k];
    }
    __syncthreads();

    // hidden: thread t computes channel t+256r for all 16 tokens
    for (int r = 0; r < 4; ++r) {
        const int hc = t + 256 * r;
        const float4* wr = reinterpret_cast<const float4*>(w1 + (size_t)hc * 256);
        float acc[16];
        #pragma unroll
        for (int u = 0; u < 16; ++u) acc[u] = 0.f;
        for (int c4 = 0; c4 < 64; ++c4) {
            float4 wv = wr[c4];
            #pragma unroll
            for (int u = 0; u < 16; ++u) {
                float4 xv = reinterpret_cast<const float4*>(xr + u * 256)[c4];
                acc[u] += xv.x * wv.x + xv.y * wv.y + xv.z * wv.z + xv.w * wv.w;
            }
        }
        const float bb = b1[hc];
        #pragma unroll
        for (int u = 0; u < 16; ++u) {
            float pre = acc[u] + bb;
            hid[u * 1024 + hc] = 0.5f * pre * (1.0f + erff(pre * 0.70710678f)); // exact gelu
        }
    }
    __syncthreads();

    // out: wave wv handles tokens wv*4..+4; lane l handles channels l+64r
    const int l = t & 63, wv = t >> 6;
    float acc2[4][4];
    #pragma unroll
    for (int u = 0; u < 4; ++u)
        #pragma unroll
        for (int r = 0; r < 4; ++r) acc2[u][r] = 0.f;

    for (int c4 = 0; c4 < 256; ++c4) {
        float4 hv[4];
        #pragma unroll
        for (int u = 0; u < 4; ++u)
            hv[u] = reinterpret_cast<const float4*>(hid + (size_t)(wv * 4 + u) * 1024)[c4];
        #pragma unroll
        for (int r = 0; r < 4; ++r) {
            float4 w4 = reinterpret_cast<const float4*>(w2 + (size_t)(l + 64 * r) * 1024)[c4];
            #pragma unroll
            for (int u = 0; u < 4; ++u)
                acc2[u][r] += hv[u].x * w4.x + hv[u].y * w4.y + hv[u].z * w4.z + hv[u].w * w4.w;
        }
    }

    #pragma unroll
    for (int u = 0; u < 4; ++u) {
        float v[4], s = 0.f, ss = 0.f;
        #pragma unroll
        for (int r = 0; r < 4; ++r) {
            v[r] = acc2[u][r] + b2[l + 64 * r];
            s += v[r]; ss += v[r] * v[r];
        }
        for (int m = 1; m < 64; m <<= 1) { s += __shfl_xor(s, m); ss += __shfl_xor(ss, m); }
        float mean = s * (1.0f / 256.0f);
        float var  = ss * (1.0f / 256.0f) - mean * mean;
        float rs   = rsqrtf(var + 1e-5f);
        float* xp = x + (tok0 + wv * 4 + u) * 256;
        #pragma unroll
        for (int r = 0; r < 4; ++r) {
            int oc = l + 64 * r;
            xp[oc] += (v[r] - mean) * rs * n2s[oc] + n2b[oc];
        }
    }
}

// ---------------- launcher ----------------
extern "C" void kernel_launch(void* const* d_in, const int* in_sizes, int n_in,
                              void* d_out, int out_size, void* d_ws, size_t ws_size,
                              hipStream_t stream) {
    (void)in_sizes; (void)n_in; (void)out_size; (void)ws_size;
    const float* tokens = (const float*)d_in[0];
    const float* qkv_w  = (const float*)d_in[3];
    const float* qkv_b  = (const float*)d_in[4];
    const float* lsc    = (const float*)d_in[5];
    const float* cw1    = (const float*)d_in[6];
    const float* cb1    = (const float*)d_in[7];
    const float* cw2    = (const float*)d_in[8];
    const float* pw     = (const float*)d_in[9];
    const float* pb     = (const float*)d_in[10];
    const float* n1s    = (const float*)d_in[11];
    const float* n1b    = (const float*)d_in[12];
    const float* mw1    = (const float*)d_in[13];
    const float* mb1    = (const float*)d_in[14];
    const float* mw2    = (const float*)d_in[15];
    const float* mb2    = (const float*)d_in[16];
    const float* n2s    = (const float*)d_in[17];
    const float* n2b    = (const float*)d_in[18];

    float* x        = (float*)d_out;
    float* attn_out = (float*)d_ws;                       // 65536*256 f32 = 64 MB
    float* biastab  = attn_out + (size_t)NTOK * C_;       // 225*8 f32

    copy_kernel<<<dim3(NTOK * C_ / 4 / 256), dim3(256), 0, stream>>>(x, tokens);

    for (int l = 0; l < 2; ++l) {
        const int shift = l ? 4 : 0;
        cpb_kernel<<<dim3(225), dim3(256), 0, stream>>>(
            cw1 + (size_t)l * 1024, cb1 + (size_t)l * 512, cw2 + (size_t)l * 4096, biastab);
        attn_kernel<<<dim3(1024), dim3(256), ATTN_LDS, stream>>>(
            x, qkv_w + (size_t)l * 196608, qkv_b + (size_t)l * 768,
            lsc + (size_t)l * 8, biastab, attn_out, shift);
        proj_kernel<<<dim3(8192), dim3(256), 0, stream>>>(
            attn_out, pw + (size_t)l * 65536, pb + (size_t)l * 256,
            n1s + (size_t)l * 256, n1b + (size_t)l * 256, x, shift);
        mlp_kernel<<<dim3(4096), dim3(256), MLP_LDS, stream>>>(
            x, mw1 + (size_t)l * 262144, mb1 + (size_t)l * 1024,
            mw2 + (size_t)l * 262144, mb2 + (size_t)l * 256,
            n2s + (size_t)l * 256, n2b + (size_t)l * 256);
    }
}

// Round 2
// 3593.153 us; speedup vs baseline: 3.1096x; 3.1096x over previous
//
#include <hip/hip_runtime.h>
#include <math.h>

// ---------------- problem constants ----------------
#define C_    256
#define NH_   8
#define N_    64      // tokens per window (8x8)
#define NTOK  65536   // B * 64 * 64

// LDS sizes (bytes)
#define ATTN_LDS ((64*256 + 3*64*36 + 64*65) * 4)   // 109,824
#define MLP_LDS  (32*256*2 + 32*1024*2)             // 81,920 (xs bf16 + hid bf16 / out f32 overlay)
#define PROJ_LDS (32*256*2 + 32*256*4)              // 49,152 (xs bf16 + out f32)

typedef __bf16 bf16x8 __attribute__((ext_vector_type(8)));
typedef float  f32x4  __attribute__((ext_vector_type(4)));
#define MFMA16(a,b,c) __builtin_amdgcn_mfma_f32_16x16x32_bf16((a),(b),(c),0,0,0)

__device__ inline ushort f2b(float f) {
    unsigned u = __builtin_bit_cast(unsigned, f);
    return (ushort)((u + 0x7fffu + ((u >> 16) & 1u)) >> 16);   // RNE
}

// ---------------- init copy ----------------
__global__ void copy_kernel(float* __restrict__ dst, const float* __restrict__ src) {
    size_t i = (size_t)blockIdx.x * blockDim.x + threadIdx.x;
    reinterpret_cast<float4*>(dst)[i] = reinterpret_cast<const float4*>(src)[i];
}

// ---------------- f32 -> bf16 weight conversion ----------------
__global__ void f2b_kernel(ushort* __restrict__ dst, const float* __restrict__ src) {
    size_t i = ((size_t)blockIdx.x * 256 + threadIdx.x) * 4;
    float4 v = *reinterpret_cast<const float4*>(src + i);
    ushort4 u = { f2b(v.x), f2b(v.y), f2b(v.z), f2b(v.w) };
    *reinterpret_cast<ushort4*>(dst + i) = u;
}

// ---------------- continuous position bias table ----------------
__global__ void cpb_kernel(const float* __restrict__ w1, const float* __restrict__ b1,
                           const float* __restrict__ w2, float* __restrict__ biastab) {
    __shared__ float red[256];
    const int e = blockIdx.x;
    const int t = threadIdx.x;
    const int p = e / 15, q = e % 15;
    const float v0 = (float)(p - 7) * (8.0f / 7.0f);
    const float v1 = (float)(q - 7) * (8.0f / 7.0f);
    const float t0 = copysignf(log2f(fabsf(v0) + 1.0f) * (1.0f / 3.0f), v0);
    const float t1 = copysignf(log2f(fabsf(v1) + 1.0f) * (1.0f / 3.0f), v1);
    const float ha = fmaxf(0.0f, t0 * w1[t * 2]         + t1 * w1[t * 2 + 1]         + b1[t]);
    const float hb = fmaxf(0.0f, t0 * w1[(t + 256) * 2] + t1 * w1[(t + 256) * 2 + 1] + b1[t + 256]);
    for (int h = 0; h < 8; ++h) {
        __syncthreads();
        red[t] = ha * w2[h * 512 + t] + hb * w2[h * 512 + t + 256];
        __syncthreads();
        for (int s = 128; s > 0; s >>= 1) {
            if (t < s) red[t] += red[t + s];
            __syncthreads();
        }
        if (t == 0) biastab[e * 8 + h] = 16.0f / (1.0f + expf(-red[0]));
    }
}

// ---------------- fused window attention (f32, unchanged except bf16 output) ----------------
__global__ __launch_bounds__(256) void attn_kernel(
    const float* __restrict__ x, const float* __restrict__ qw,
    const float* __restrict__ qb, const float* __restrict__ lsc,
    const float* __restrict__ biastab, ushort* __restrict__ ao, int shift)
{
    extern __shared__ float lds[];
    float* xs = lds;                  // [64][256]
    float* qs = lds + 64 * 256;       // [64][36]
    float* ks = qs + 64 * 36;
    float* vs = ks + 64 * 36;
    float* sc = vs + 64 * 36;         // [64][65]

    const int t   = threadIdx.x;
    const int win = blockIdx.x;
    const int b = win >> 6, wh = (win >> 3) & 7, ww = win & 7;

    {
        int n = t >> 2, qt = t & 3;
        int i = n >> 3, j = n & 7;
        int r = (wh * 8 + i + shift) & 63;
        int c = (ww * 8 + j + shift) & 63;
        const float4* src = reinterpret_cast<const float4*>(
            x + ((size_t)(b * 4096 + r * 64 + c)) * 256) + qt * 16;
        float4* dst = reinterpret_cast<float4*>(xs + n * 256) + qt * 16;
        #pragma unroll
        for (int k2 = 0; k2 < 16; ++k2) dst[k2] = src[k2];
    }
    __syncthreads();

    const int d = t & 31, ng = t >> 5;
    const int nq = t >> 2, quad = t & 3;
    const int i1 = nq >> 3, j1 = nq & 7;

    for (int h = 0; h < 8; ++h) {
        float aq[8], ak[8], av[8];
        #pragma unroll
        for (int u = 0; u < 8; ++u) { aq[u] = 0.f; ak[u] = 0.f; av[u] = 0.f; }
        const float4* wq = reinterpret_cast<const float4*>(qw + (size_t)(h * 32 + d) * 256);
        const float4* wk = reinterpret_cast<const float4*>(qw + (size_t)(256 + h * 32 + d) * 256);
        const float4* wv = reinterpret_cast<const float4*>(qw + (size_t)(512 + h * 32 + d) * 256);
        for (int c4 = 0; c4 < 64; ++c4) {
            float4 q4 = wq[c4], k4 = wk[c4], v4 = wv[c4];
            #pragma unroll
            for (int u = 0; u < 8; ++u) {
                float4 xv = reinterpret_cast<const float4*>(xs + (ng * 8 + u) * 256)[c4];
                aq[u] += xv.x * q4.x + xv.y * q4.y + xv.z * q4.z + xv.w * q4.w;
                ak[u] += xv.x * k4.x + xv.y * k4.y + xv.z * k4.z + xv.w * k4.w;
                av[u] += xv.x * v4.x + xv.y * v4.y + xv.z * v4.z + xv.w * v4.w;
            }
        }
        const float bq = qb[h * 32 + d], bk = qb[256 + h * 32 + d], bv = qb[512 + h * 32 + d];
        #pragma unroll
        for (int u = 0; u < 8; ++u) {
            int n = ng * 8 + u;
            qs[n * 36 + d] = aq[u] + bq;
            ks[n * 36 + d] = ak[u] + bk;
            vs[n * 36 + d] = av[u] + bv;
        }
        __syncthreads();

        if (t < 128) {
            float* pp = (t < 64) ? qs : ks;
            int n = t & 63;
            float s = 0.f;
            #pragma unroll
            for (int k4 = 0; k4 < 8; ++k4) {
                float4 v4 = reinterpret_cast<float4*>(pp + n * 36)[k4];
                s += v4.x * v4.x + v4.y * v4.y + v4.z * v4.z + v4.w * v4.w;
            }
            float inv = 1.0f / (sqrtf(s) + 1e-12f);
            #pragma unroll
            for (int k4 = 0; k4 < 8; ++k4) {
                float4 v4 = reinterpret_cast<float4*>(pp + n * 36)[k4];
                v4.x *= inv; v4.y *= inv; v4.z *= inv; v4.w *= inv;
                reinterpret_cast<float4*>(pp + n * 36)[k4] = v4;
            }
        }
        __syncthreads();

        {
            const float scale = expf(fminf(lsc[h], 4.6051702f));
            int reg_n = 0;
            if (shift) {
                int pr = wh * 8 + i1, pc = ww * 8 + j1;
                reg_n = ((pr < 56) ? 0 : ((pr < 60) ? 1 : 2)) * 3 +
                        ((pc < 56) ? 0 : ((pc < 60) ? 1 : 2));
            }
            const int m0 = quad * 16;
            for (int m = m0; m < m0 + 16; ++m) {
                float dot = 0.f;
                #pragma unroll
                for (int k4 = 0; k4 < 8; ++k4) {
                    float4 qv = reinterpret_cast<const float4*>(qs + nq * 36)[k4];
                    float4 kv = reinterpret_cast<const float4*>(ks + m * 36)[k4];
                    dot += qv.x * kv.x + qv.y * kv.y + qv.z * kv.z + qv.w * kv.w;
                }
                float lg = dot * scale;
                int i2 = m >> 3, j2 = m & 7;
                lg += biastab[((i1 - i2 + 7) * 15 + (j1 - j2 + 7)) * 8 + h];
                if (shift) {
                    int pr = wh * 8 + i2, pc = ww * 8 + j2;
                    int reg_m = ((pr < 56) ? 0 : ((pr < 60) ? 1 : 2)) * 3 +
                                ((pc < 56) ? 0 : ((pc < 60) ? 1 : 2));
                    if (reg_m != reg_n) lg -= 100.f;
                }
                sc[nq * 65 + m] = lg;
            }
        }
        __syncthreads();

        if (t < 64) {
            float mx = -1e30f;
            for (int m = 0; m < 64; ++m) mx = fmaxf(mx, sc[t * 65 + m]);
            float s = 0.f;
            for (int m = 0; m < 64; ++m) { float e = expf(sc[t * 65 + m] - mx); sc[t * 65 + m] = e; s += e; }
            float inv = 1.0f / s;
            for (int m = 0; m < 64; ++m) sc[t * 65 + m] *= inv;
        }
        __syncthreads();

        {
            const int d0 = quad * 8;
            float o[8];
            #pragma unroll
            for (int u = 0; u < 8; ++u) o[u] = 0.f;
            for (int m = 0; m < 64; ++m) {
                float p = sc[nq * 65 + m];
                float4 v0 = *reinterpret_cast<const float4*>(vs + m * 36 + d0);
                float4 v1 = *reinterpret_cast<const float4*>(vs + m * 36 + d0 + 4);
                o[0] += p * v0.x; o[1] += p * v0.y; o[2] += p * v0.z; o[3] += p * v0.w;
                o[4] += p * v1.x; o[5] += p * v1.y; o[6] += p * v1.z; o[7] += p * v1.w;
            }
            ushort* dst = ao + ((size_t)(win * 64 + nq)) * 256 + h * 32 + d0;
            ushort4 u0 = { f2b(o[0]), f2b(o[1]), f2b(o[2]), f2b(o[3]) };
            ushort4 u1 = { f2b(o[4]), f2b(o[5]), f2b(o[6]), f2b(o[7]) };
            *reinterpret_cast<ushort4*>(dst)     = u0;
            *reinterpret_cast<ushort4*>(dst + 4) = u1;
        }
        __syncthreads();
    }
}

// ---------------- proj (bf16 MFMA) + bias + post-LN + un-roll scatter + residual ----------------
// 32 tokens/block, 4 waves; wave w owns output cols [w*64, w*64+64)
__global__ __launch_bounds__(256, 3) void proj_mfma_kernel(
    const ushort* __restrict__ aob, const ushort* __restrict__ pwb,
    const float* __restrict__ pb, const float* __restrict__ n1s,
    const float* __restrict__ n1b, float* __restrict__ x, int shift)
{
    extern __shared__ ushort smem[];
    ushort* xs   = smem;                       // [32][256] bf16, swizzled
    float*  outT = (float*)(smem + 32 * 256);  // [32][256] f32

    const int t = threadIdx.x;
    const size_t tok0 = (size_t)blockIdx.x * 32;

    {   // stage 32 rows of attn_out (bf16) into swizzled LDS
        int row = t >> 3, seg = t & 7;
        const ushort4* src = reinterpret_cast<const ushort4*>(aob + (tok0 + row) * 256 + seg * 32);
        #pragma unroll
        for (int c4 = 0; c4 < 8; ++c4) {
            ushort4 v = src[c4];
            int col = seg * 32 + c4 * 4;
            *reinterpret_cast<ushort4*>(xs + row * 256 + (col ^ ((row & 7) << 3))) = v;
        }
    }
    __syncthreads();

    const int w = t >> 6, l = t & 63, lr = l & 15, lk = (l >> 4) * 8;
    const int aswz = (lr & 7) << 3;
    f32x4 acc[2][4];
    const f32x4 zf = { 0.f, 0.f, 0.f, 0.f };
    #pragma unroll
    for (int mf = 0; mf < 2; ++mf)
        #pragma unroll
        for (int nf = 0; nf < 4; ++nf) acc[mf][nf] = zf;

    for (int kt = 0; kt < 8; ++kt) {
        int k0 = kt * 32 + lk;
        bf16x8 a0 = *reinterpret_cast<const bf16x8*>(xs + lr * 256        + (k0 ^ aswz));
        bf16x8 a1 = *reinterpret_cast<const bf16x8*>(xs + (16 + lr) * 256 + (k0 ^ aswz));
        #pragma unroll
        for (int nf = 0; nf < 4; ++nf) {
            bf16x8 b = *reinterpret_cast<const bf16x8*>(pwb + (size_t)(w * 64 + nf * 16 + lr) * 256 + k0);
            acc[0][nf] = MFMA16(a0, b, acc[0][nf]);
            acc[1][nf] = MFMA16(a1, b, acc[1][nf]);
        }
    }

    // write acc + bias to out tile
    #pragma unroll
    for (int nf = 0; nf < 4; ++nf) {
        int c = w * 64 + nf * 16 + lr;
        float bb = pb[c];
        #pragma unroll
        for (int mf = 0; mf < 2; ++mf)
            #pragma unroll
            for (int r = 0; r < 4; ++r)
                outT[(mf * 16 + (l >> 4) * 4 + r) * 256 + c] = acc[mf][nf][r] + bb;
    }
    __syncthreads();

    // LN + scatter residual: wave w handles tokens w*8 .. w*8+7
    for (int u = 0; u < 8; ++u) {
        int tk = w * 8 + u;
        float v0 = outT[tk * 256 + l];
        float v1 = outT[tk * 256 + l + 64];
        float v2 = outT[tk * 256 + l + 128];
        float v3 = outT[tk * 256 + l + 192];
        float s = v0 + v1 + v2 + v3, ss = v0 * v0 + v1 * v1 + v2 * v2 + v3 * v3;
        for (int m = 1; m < 64; m <<= 1) { s += __shfl_xor(s, m); ss += __shfl_xor(ss, m); }
        float mean = s * (1.0f / 256.0f);
        float var  = ss * (1.0f / 256.0f) - mean * mean;
        float rs   = rsqrtf(var + 1e-5f);

        size_t gt = tok0 + tk;
        int win = (int)(gt >> 6), n = (int)(gt & 63);
        int b = win >> 6, wh = (win >> 3) & 7, ww = win & 7, i = n >> 3, j = n & 7;
        int pr = (wh * 8 + i + shift) & 63;
        int pc = (ww * 8 + j + shift) & 63;
        float* xp = x + ((size_t)(b * 4096 + pr * 64 + pc)) * 256;
        xp[l]       += (v0 - mean) * rs * n1s[l]       + n1b[l];
        xp[l + 64]  += (v1 - mean) * rs * n1s[l + 64]  + n1b[l + 64];
        xp[l + 128] += (v2 - mean) * rs * n1s[l + 128] + n1b[l + 128];
        xp[l + 192] += (v3 - mean) * rs * n1s[l + 192] + n1b[l + 192];
    }
}

// ---------------- fused MLP (bf16 MFMA): 256 -> 1024 gelu -> 256, post-LN, residual ----------------
// 32 tokens/block, 4 waves; GEMM1: wave w owns hidden cols [w*256,w*256+256); GEMM2: cols [w*64,+64)
__global__ __launch_bounds__(256, 2) void mlp_mfma_kernel(
    float* __restrict__ x, const ushort* __restrict__ w1b, const float* __restrict__ b1,
    const ushort* __restrict__ w2b, const float* __restrict__ b2,
    const float* __restrict__ n2s, const float* __restrict__ n2b)
{
    extern __shared__ ushort smem[];
    ushort* xs  = smem;             // [32][256] bf16, swizzled
    ushort* hid = smem + 32 * 256;  // [32][1024] bf16, swizzled
    float*  outT = (float*)hid;     // [32][256] f32 overlay (after GEMM2)

    const int t = threadIdx.x;
    const size_t tok0 = (size_t)blockIdx.x * 32;

    {   // stage 32 rows of x (f32 -> bf16) into swizzled LDS
        int row = t >> 3, seg = t & 7;
        const float4* src = reinterpret_cast<const float4*>(x + (tok0 + row) * 256 + seg * 32);
        #pragma unroll
        for (int c4 = 0; c4 < 8; ++c4) {
            float4 v = src[c4];
            int col = seg * 32 + c4 * 4;
            ushort4 u = { f2b(v.x), f2b(v.y), f2b(v.z), f2b(v.w) };
            *reinterpret_cast<ushort4*>(xs + row * 256 + (col ^ ((row & 7) << 3))) = u;
        }
    }
    __syncthreads();

    const int w = t >> 6, l = t & 63, lr = l & 15, lk = (l >> 4) * 8;
    const int aswz = (lr & 7) << 3;
    const int n0 = w * 256;
    const f32x4 zf = { 0.f, 0.f, 0.f, 0.f };

    // ---- GEMM1: hidden[32][1024] = x @ w1^T ----
    {
        f32x4 acc[2][16];
        #pragma unroll
        for (int mf = 0; mf < 2; ++mf)
            #pragma unroll
            for (int nf = 0; nf < 16; ++nf) acc[mf][nf] = zf;

        for (int kt = 0; kt < 8; ++kt) {
            int k0 = kt * 32 + lk;
            bf16x8 a0 = *reinterpret_cast<const bf16x8*>(xs + lr * 256        + (k0 ^ aswz));
            bf16x8 a1 = *reinterpret_cast<const bf16x8*>(xs + (16 + lr) * 256 + (k0 ^ aswz));
            #pragma unroll
            for (int nf = 0; nf < 16; ++nf) {
                bf16x8 b = *reinterpret_cast<const bf16x8*>(w1b + (size_t)(n0 + nf * 16 + lr) * 256 + k0);
                acc[0][nf] = MFMA16(a0, b, acc[0][nf]);
                acc[1][nf] = MFMA16(a1, b, acc[1][nf]);
            }
        }

        // gelu(acc + b1) -> hid (swizzled bf16)
        #pragma unroll
        for (int nf = 0; nf < 16; ++nf) {
            int hcol = n0 + nf * 16 + lr;
            float bb = b1[hcol];
            #pragma unroll
            for (int mf = 0; mf < 2; ++mf)
                #pragma unroll
                for (int r = 0; r < 4; ++r) {
                    int hrow = mf * 16 + (l >> 4) * 4 + r;
                    float pre = acc[mf][nf][r] + bb;
                    float g = 0.5f * pre * (1.0f + erff(pre * 0.70710678f));
                    hid[hrow * 1024 + (hcol ^ ((hrow & 7) << 3))] = f2b(g);
                }
        }
    }
    __syncthreads();

    // ---- GEMM2: out[32][256] = hid @ w2^T ----
    f32x4 acc2[2][4];
    #pragma unroll
    for (int mf = 0; mf < 2; ++mf)
        #pragma unroll
        for (int nf = 0; nf < 4; ++nf) acc2[mf][nf] = zf;

    for (int kt = 0; kt < 32; ++kt) {
        int k0 = kt * 32 + lk;
        bf16x8 a0 = *reinterpret_cast<const bf16x8*>(hid + lr * 1024        + (k0 ^ aswz));
        bf16x8 a1 = *reinterpret_cast<const bf16x8*>(hid + (16 + lr) * 1024 + (k0 ^ aswz));
        #pragma unroll
        for (int nf = 0; nf < 4; ++nf) {
            bf16x8 b = *reinterpret_cast<const bf16x8*>(w2b + (size_t)(w * 64 + nf * 16 + lr) * 1024 + k0);
            acc2[0][nf] = MFMA16(a0, b, acc2[0][nf]);
            acc2[1][nf] = MFMA16(a1, b, acc2[1][nf]);
        }
    }
    __syncthreads();   // all hid reads done before overlaying outT

    #pragma unroll
    for (int nf = 0; nf < 4; ++nf) {
        int c = w * 64 + nf * 16 + lr;
        float bb = b2[c];
        #pragma unroll
        for (int mf = 0; mf < 2; ++mf)
            #pragma unroll
            for (int r = 0; r < 4; ++r)
                outT[(mf * 16 + (l >> 4) * 4 + r) * 256 + c] = acc2[mf][nf][r] + bb;
    }
    __syncthreads();

    // LN + residual: wave w handles tokens w*8 .. w*8+7
    for (int u = 0; u < 8; ++u) {
        int tk = w * 8 + u;
        float v0 = outT[tk * 256 + l];
        float v1 = outT[tk * 256 + l + 64];
        float v2 = outT[tk * 256 + l + 128];
        float v3 = outT[tk * 256 + l + 192];
        float s = v0 + v1 + v2 + v3, ss = v0 * v0 + v1 * v1 + v2 * v2 + v3 * v3;
        for (int m = 1; m < 64; m <<= 1) { s += __shfl_xor(s, m); ss += __shfl_xor(ss, m); }
        float mean = s * (1.0f / 256.0f);
        float var  = ss * (1.0f / 256.0f) - mean * mean;
        float rs   = rsqrtf(var + 1e-5f);
        float* xp = x + (tok0 + tk) * 256;
        xp[l]       += (v0 - mean) * rs * n2s[l]       + n2b[l];
        xp[l + 64]  += (v1 - mean) * rs * n2s[l + 64]  + n2b[l + 64];
        xp[l + 128] += (v2 - mean) * rs * n2s[l + 128] + n2b[l + 128];
        xp[l + 192] += (v3 - mean) * rs * n2s[l + 192] + n2b[l + 192];
    }
}

// ---------------- launcher ----------------
extern "C" void kernel_launch(void* const* d_in, const int* in_sizes, int n_in,
                              void* d_out, int out_size, void* d_ws, size_t ws_size,
                              hipStream_t stream) {
    (void)in_sizes; (void)n_in; (void)out_size; (void)ws_size;
    const float* tokens = (const float*)d_in[0];
    const float* qkv_w  = (const float*)d_in[3];
    const float* qkv_b  = (const float*)d_in[4];
    const float* lsc    = (const float*)d_in[5];
    const float* cw1    = (const float*)d_in[6];
    const float* cb1    = (const float*)d_in[7];
    const float* cw2    = (const float*)d_in[8];
    const float* pw     = (const float*)d_in[9];
    const float* pb     = (const float*)d_in[10];
    const float* n1s    = (const float*)d_in[11];
    const float* n1b    = (const float*)d_in[12];
    const float* mw1    = (const float*)d_in[13];
    const float* mb1    = (const float*)d_in[14];
    const float* mw2    = (const float*)d_in[15];
    const float* mb2    = (const float*)d_in[16];
    const float* n2s    = (const float*)d_in[17];
    const float* n2b    = (const float*)d_in[18];

    float* x = (float*)d_out;

    // workspace layout (all 16B aligned)
    ushort* attn_out = (ushort*)d_ws;                              // 16,777,216 bf16 = 32 MB
    float*  biastab  = (float*)((char*)d_ws + (size_t)NTOK * C_ * 2);  // 1800 f32 (7200 B)
    ushort* pwb      = (ushort*)((char*)biastab + 7200);           // 2*256*256
    ushort* w1b      = pwb + 2 * 256 * 256;                        // 2*1024*256
    ushort* w2b      = w1b + 2 * 1024 * 256;                       // 2*256*1024

    // convert all weights to bf16 (layouts preserved: N x K row-major)
    f2b_kernel<<<dim3(2 * 256 * 256 / 1024),  dim3(256), 0, stream>>>(pwb, pw);
    f2b_kernel<<<dim3(2 * 1024 * 256 / 1024), dim3(256), 0, stream>>>(w1b, mw1);
    f2b_kernel<<<dim3(2 * 256 * 1024 / 1024), dim3(256), 0, stream>>>(w2b, mw2);

    copy_kernel<<<dim3(NTOK * C_ / 4 / 256), dim3(256), 0, stream>>>(x, tokens);

    for (int l = 0; l < 2; ++l) {
        const int shift = l ? 4 : 0;
        cpb_kernel<<<dim3(225), dim3(256), 0, stream>>>(
            cw1 + (size_t)l * 1024, cb1 + (size_t)l * 512, cw2 + (size_t)l * 4096, biastab);
        attn_kernel<<<dim3(1024), dim3(256), ATTN_LDS, stream>>>(
            x, qkv_w + (size_t)l * 196608, qkv_b + (size_t)l * 768,
            lsc + (size_t)l * 8, biastab, attn_out, shift);
        proj_mfma_kernel<<<dim3(NTOK / 32), dim3(256), PROJ_LDS, stream>>>(
            attn_out, pwb + (size_t)l * 65536, pb + (size_t)l * 256,
            n1s + (size_t)l * 256, n1b + (size_t)l * 256, x, shift);
        mlp_mfma_kernel<<<dim3(NTOK / 32), dim3(256), MLP_LDS, stream>>>(
            x, w1b + (size_t)l * 262144, mb1 + (size_t)l * 1024,
            w2b + (size_t)l * 262144, mb2 + (size_t)l * 256,
            n2s + (size_t)l * 256, n2b + (size_t)l * 256);
    }
}

// Round 3
// 1221.583 us; speedup vs baseline: 9.1466x; 2.9414x over previous
//
#include <hip/hip_runtime.h>
#include <math.h>

// ---------------- problem constants ----------------
#define C_    256
#define NH_   8
#define N_    64      // tokens per window (8x8)
#define NTOK  65536   // B * 64 * 64

// LDS sizes (bytes)
#define MLP_LDS  (32*256*2 + 32*1024*2)             // 81,920
#define PROJ_LDS (32*256*2 + 32*256*4)              // 49,152
#define ATTN_LDS ((64*256 + 2*64*36 + 32*68 + 64*72) * 2)  // 55,552

typedef __bf16 bf16x8 __attribute__((ext_vector_type(8)));
typedef float  f32x4  __attribute__((ext_vector_type(4)));
#define MFMA16(a,b,c) __builtin_amdgcn_mfma_f32_16x16x32_bf16((a),(b),(c),0,0,0)

__device__ inline ushort f2b(float f) {
    unsigned u = __builtin_bit_cast(unsigned, f);
    return (ushort)((u + 0x7fffu + ((u >> 16) & 1u)) >> 16);   // RNE
}

// ---------------- init copy ----------------
__global__ void copy_kernel(float* __restrict__ dst, const float* __restrict__ src) {
    size_t i = (size_t)blockIdx.x * blockDim.x + threadIdx.x;
    reinterpret_cast<float4*>(dst)[i] = reinterpret_cast<const float4*>(src)[i];
}

// ---------------- f32 -> bf16 weight conversion ----------------
__global__ void f2b_kernel(ushort* __restrict__ dst, const float* __restrict__ src) {
    size_t i = ((size_t)blockIdx.x * 256 + threadIdx.x) * 4;
    float4 v = *reinterpret_cast<const float4*>(src + i);
    ushort4 u = { f2b(v.x), f2b(v.y), f2b(v.z), f2b(v.w) };
    *reinterpret_cast<ushort4*>(dst + i) = u;
}

// ---------------- continuous position bias table ----------------
__global__ void cpb_kernel(const float* __restrict__ w1, const float* __restrict__ b1,
                           const float* __restrict__ w2, float* __restrict__ biastab) {
    __shared__ float red[256];
    const int e = blockIdx.x;
    const int t = threadIdx.x;
    const int p = e / 15, q = e % 15;
    const float v0 = (float)(p - 7) * (8.0f / 7.0f);
    const float v1 = (float)(q - 7) * (8.0f / 7.0f);
    const float t0 = copysignf(log2f(fabsf(v0) + 1.0f) * (1.0f / 3.0f), v0);
    const float t1 = copysignf(log2f(fabsf(v1) + 1.0f) * (1.0f / 3.0f), v1);
    const float ha = fmaxf(0.0f, t0 * w1[t * 2]         + t1 * w1[t * 2 + 1]         + b1[t]);
    const float hb = fmaxf(0.0f, t0 * w1[(t + 256) * 2] + t1 * w1[(t + 256) * 2 + 1] + b1[t + 256]);
    for (int h = 0; h < 8; ++h) {
        __syncthreads();
        red[t] = ha * w2[h * 512 + t] + hb * w2[h * 512 + t + 256];
        __syncthreads();
        for (int s = 128; s > 0; s >>= 1) {
            if (t < s) red[t] += red[t + s];
            __syncthreads();
        }
        if (t == 0) biastab[e * 8 + h] = 16.0f / (1.0f + expf(-red[0]));
    }
}

// ---------------- expand bias to [8][64][64] ----------------
__global__ void biasx_kernel(const float* __restrict__ biastab, float* __restrict__ biasx) {
    int h = blockIdx.x >> 6, n = blockIdx.x & 63, m = threadIdx.x;
    int idx = ((n >> 3) - (m >> 3) + 7) * 15 + ((n & 7) - (m & 7) + 7);
    biasx[((size_t)(h * 64 + n)) * 64 + m] = biastab[idx * 8 + h];
}

// ---------------- fused window attention (bf16 MFMA) ----------------
// one block per window, 4 waves; wave w owns token rows [w*16, w*16+16)
__global__ __launch_bounds__(256, 2) void attn_mfma_kernel(
    const float* __restrict__ x, const ushort* __restrict__ qwb,
    const float* __restrict__ qb, const float* __restrict__ lsc,
    const float* __restrict__ biasx, ushort* __restrict__ ao, int shift)
{
    extern __shared__ ushort sm[];
    ushort* xs = sm;                    // [64][256] bf16, swizzled
    ushort* qm = sm + 64 * 256;         // [64][36]
    ushort* km = qm + 64 * 36;          // [64][36]
    ushort* vT = km + 64 * 36;          // [32][68]  (chan-major)
    ushort* Pm = vT + 32 * 68;          // [64][72]

    const int t   = threadIdx.x;
    const int win = blockIdx.x;
    const int b = win >> 6, wh = (win >> 3) & 7, ww = win & 7;

    // ---- stage window tokens (f32 -> bf16, rolled, swizzled) ----
    {
        int row = t >> 2, seg = t & 3;
        int i = row >> 3, j = row & 7;
        int r = (wh * 8 + i + shift) & 63;
        int c = (ww * 8 + j + shift) & 63;
        const float4* src = reinterpret_cast<const float4*>(
            x + ((size_t)(b * 4096 + r * 64 + c)) * 256 + seg * 64);
        #pragma unroll
        for (int k4 = 0; k4 < 16; ++k4) {
            float4 v = src[k4];
            int col = seg * 64 + k4 * 4;
            ushort4 u = { f2b(v.x), f2b(v.y), f2b(v.z), f2b(v.w) };
            *reinterpret_cast<ushort4*>(xs + row * 256 + (col ^ ((row & 7) << 3))) = u;
        }
    }
    __syncthreads();

    const int w = t >> 6, l = t & 63, lr = l & 15, lg = l >> 4;
    const int wtile = w * 16;
    const int aswz = (lr & 7) << 3;
    const f32x4 zf = { 0.f, 0.f, 0.f, 0.f };

    // hoist A-fragments (same for every head): 8 k-steps
    bf16x8 af[8];
    #pragma unroll
    for (int kt = 0; kt < 8; ++kt) {
        int k0 = kt * 32 + lg * 8;
        af[kt] = *reinterpret_cast<const bf16x8*>(xs + (wtile + lr) * 256 + (k0 ^ aswz));
    }

    // token rows this lane owns in C/D layout
    int tokr[4];
    #pragma unroll
    for (int r = 0; r < 4; ++r) tokr[r] = wtile + lg * 4 + r;
    // shift-mask region of each owned row (rolled coords)
    int regr[4];
    #pragma unroll
    for (int r = 0; r < 4; ++r) {
        int pr = wh * 8 + (tokr[r] >> 3), pc = ww * 8 + (tokr[r] & 7);
        regr[r] = ((pr < 56) ? 0 : ((pr < 60) ? 1 : 2)) * 3 +
                  ((pc < 56) ? 0 : ((pc < 60) ? 1 : 2));
    }

    for (int h = 0; h < 8; ++h) {
        // ---- QKV GEMM: M=16 (wave tile), N=96 (q|k|v), K=256 ----
        f32x4 acc[6];
        #pragma unroll
        for (int nf = 0; nf < 6; ++nf) acc[nf] = zf;

        int brow[6];
        #pragma unroll
        for (int nf = 0; nf < 6; ++nf)
            brow[nf] = (nf >> 1) * 256 + h * 32 + (nf & 1) * 16 + lr;

        for (int kt = 0; kt < 8; ++kt) {
            int k0 = kt * 32 + lg * 8;
            #pragma unroll
            for (int nf = 0; nf < 6; ++nf) {
                bf16x8 bfr = *reinterpret_cast<const bf16x8*>(qwb + (size_t)brow[nf] * 256 + k0);
                acc[nf] = MFMA16(af[kt], bfr, acc[nf]);
            }
        }

        // ---- bias add + q/k L2-normalize (in-register, 16-lane reductions) ----
        const float bq0 = qb[h * 32 + lr],       bq1 = qb[h * 32 + 16 + lr];
        const float bk0 = qb[256 + h * 32 + lr], bk1 = qb[256 + h * 32 + 16 + lr];
        const float bv0 = qb[512 + h * 32 + lr], bv1 = qb[512 + h * 32 + 16 + lr];

        float qv0[4], qv1[4], kv0[4], kv1[4], sq[4], sk[4];
        #pragma unroll
        for (int r = 0; r < 4; ++r) {
            qv0[r] = acc[0][r] + bq0; qv1[r] = acc[1][r] + bq1;
            kv0[r] = acc[2][r] + bk0; kv1[r] = acc[3][r] + bk1;
            sq[r] = qv0[r] * qv0[r] + qv1[r] * qv1[r];
            sk[r] = kv0[r] * kv0[r] + kv1[r] * kv1[r];
        }
        #pragma unroll
        for (int m = 1; m < 16; m <<= 1) {
            #pragma unroll
            for (int r = 0; r < 4; ++r) { sq[r] += __shfl_xor(sq[r], m); sk[r] += __shfl_xor(sk[r], m); }
        }
        #pragma unroll
        for (int r = 0; r < 4; ++r) {
            float qi = 1.0f / (sqrtf(sq[r]) + 1e-12f);
            float ki = 1.0f / (sqrtf(sk[r]) + 1e-12f);
            int tok = tokr[r];
            qm[tok * 36 + lr]      = f2b(qv0[r] * qi);
            qm[tok * 36 + 16 + lr] = f2b(qv1[r] * qi);
            km[tok * 36 + lr]      = f2b(kv0[r] * ki);
            km[tok * 36 + 16 + lr] = f2b(kv1[r] * ki);
        }
        {   // v transposed: vT[chan][token], 4 consecutive tokens per reg -> 8B store
            ushort4 u0 = { f2b(acc[4][0] + bv0), f2b(acc[4][1] + bv0), f2b(acc[4][2] + bv0), f2b(acc[4][3] + bv0) };
            ushort4 u1 = { f2b(acc[5][0] + bv1), f2b(acc[5][1] + bv1), f2b(acc[5][2] + bv1), f2b(acc[5][3] + bv1) };
            *reinterpret_cast<ushort4*>(vT + lr * 68        + wtile + lg * 4) = u0;
            *reinterpret_cast<ushort4*>(vT + (16 + lr) * 68 + wtile + lg * 4) = u1;
        }
        __syncthreads();

        // ---- S = (q k^T) * scale + bias + mask : M=16/wave, N=64, K=32 ----
        f32x4 sacc[4];
        {
            bf16x8 aq = *reinterpret_cast<const bf16x8*>(qm + (wtile + lr) * 36 + lg * 8);
            #pragma unroll
            for (int nf = 0; nf < 4; ++nf) {
                bf16x8 bk = *reinterpret_cast<const bf16x8*>(km + (nf * 16 + lr) * 36 + lg * 8);
                sacc[nf] = MFMA16(aq, bk, zf);
            }
        }
        const float scale = __expf(fminf(lsc[h], 4.6051702f));
        const float* brow0 = biasx + ((size_t)(h * 64 + tokr[0])) * 64;

        float mx[4] = { -1e30f, -1e30f, -1e30f, -1e30f };
        #pragma unroll
        for (int nf = 0; nf < 4; ++nf) {
            int kc = nf * 16 + lr;
            int regc = 0;
            if (shift) {
                int pr = wh * 8 + (kc >> 3), pc = ww * 8 + (kc & 7);
                regc = ((pr < 56) ? 0 : ((pr < 60) ? 1 : 2)) * 3 +
                       ((pc < 56) ? 0 : ((pc < 60) ? 1 : 2));
            }
            #pragma unroll
            for (int r = 0; r < 4; ++r) {
                float v = sacc[nf][r] * scale + brow0[(size_t)r * 64 + kc];
                if (shift && regc != regr[r]) v -= 100.0f;
                sacc[nf][r] = v;
                mx[r] = fmaxf(mx[r], v);
            }
        }
        #pragma unroll
        for (int m = 1; m < 16; m <<= 1)
            #pragma unroll
            for (int r = 0; r < 4; ++r) mx[r] = fmaxf(mx[r], __shfl_xor(mx[r], m));

        float sum[4] = { 0.f, 0.f, 0.f, 0.f };
        #pragma unroll
        for (int nf = 0; nf < 4; ++nf)
            #pragma unroll
            for (int r = 0; r < 4; ++r) {
                float e = __expf(sacc[nf][r] - mx[r]);
                sacc[nf][r] = e;
                sum[r] += e;
            }
        #pragma unroll
        for (int m = 1; m < 16; m <<= 1)
            #pragma unroll
            for (int r = 0; r < 4; ++r) sum[r] += __shfl_xor(sum[r], m);
        float inv[4];
        #pragma unroll
        for (int r = 0; r < 4; ++r) inv[r] = 1.0f / sum[r];

        // write unnormalized P (bf16); 1/sum folded into PV epilogue
        #pragma unroll
        for (int nf = 0; nf < 4; ++nf)
            #pragma unroll
            for (int r = 0; r < 4; ++r)
                Pm[tokr[r] * 72 + nf * 16 + lr] = f2b(sacc[nf][r]);
        __syncthreads();

        // ---- PV: M=16/wave, N=32, K=64 ----
        f32x4 oacc[2] = { zf, zf };
        #pragma unroll
        for (int ks = 0; ks < 2; ++ks) {
            bf16x8 ap = *reinterpret_cast<const bf16x8*>(Pm + (wtile + lr) * 72 + ks * 32 + lg * 8);
            #pragma unroll
            for (int nf = 0; nf < 2; ++nf) {
                bf16x8 bv = *reinterpret_cast<const bf16x8*>(vT + (nf * 16 + lr) * 68 + ks * 32 + lg * 8);
                oacc[nf] = MFMA16(ap, bv, oacc[nf]);
            }
        }

        // ---- scatter output head slice (bf16) ----
        #pragma unroll
        for (int nf = 0; nf < 2; ++nf)
            #pragma unroll
            for (int r = 0; r < 4; ++r)
                ao[((size_t)(win * 64 + tokr[r])) * 256 + h * 32 + nf * 16 + lr] = f2b(oacc[nf][r] * inv[r]);
        __syncthreads();   // protect qm/km/vT/Pm before next head
    }
}

// ---------------- proj (bf16 MFMA) + bias + post-LN + un-roll scatter + residual ----------------
__global__ __launch_bounds__(256, 3) void proj_mfma_kernel(
    const ushort* __restrict__ aob, const ushort* __restrict__ pwb,
    const float* __restrict__ pb, const float* __restrict__ n1s,
    const float* __restrict__ n1b, float* __restrict__ x, int shift)
{
    extern __shared__ ushort smem[];
    ushort* xs   = smem;                       // [32][256] bf16, swizzled
    float*  outT = (float*)(smem + 32 * 256);  // [32][256] f32

    const int t = threadIdx.x;
    const size_t tok0 = (size_t)blockIdx.x * 32;

    {
        int row = t >> 3, seg = t & 7;
        const ushort4* src = reinterpret_cast<const ushort4*>(aob + (tok0 + row) * 256 + seg * 32);
        #pragma unroll
        for (int c4 = 0; c4 < 8; ++c4) {
            ushort4 v = src[c4];
            int col = seg * 32 + c4 * 4;
            *reinterpret_cast<ushort4*>(xs + row * 256 + (col ^ ((row & 7) << 3))) = v;
        }
    }
    __syncthreads();

    const int w = t >> 6, l = t & 63, lr = l & 15, lk = (l >> 4) * 8;
    const int aswz = (lr & 7) << 3;
    f32x4 acc[2][4];
    const f32x4 zf = { 0.f, 0.f, 0.f, 0.f };
    #pragma unroll
    for (int mf = 0; mf < 2; ++mf)
        #pragma unroll
        for (int nf = 0; nf < 4; ++nf) acc[mf][nf] = zf;

    for (int kt = 0; kt < 8; ++kt) {
        int k0 = kt * 32 + lk;
        bf16x8 a0 = *reinterpret_cast<const bf16x8*>(xs + lr * 256        + (k0 ^ aswz));
        bf16x8 a1 = *reinterpret_cast<const bf16x8*>(xs + (16 + lr) * 256 + (k0 ^ aswz));
        #pragma unroll
        for (int nf = 0; nf < 4; ++nf) {
            bf16x8 b = *reinterpret_cast<const bf16x8*>(pwb + (size_t)(w * 64 + nf * 16 + lr) * 256 + k0);
            acc[0][nf] = MFMA16(a0, b, acc[0][nf]);
            acc[1][nf] = MFMA16(a1, b, acc[1][nf]);
        }
    }

    #pragma unroll
    for (int nf = 0; nf < 4; ++nf) {
        int c = w * 64 + nf * 16 + lr;
        float bb = pb[c];
        #pragma unroll
        for (int mf = 0; mf < 2; ++mf)
            #pragma unroll
            for (int r = 0; r < 4; ++r)
                outT[(mf * 16 + (l >> 4) * 4 + r) * 256 + c] = acc[mf][nf][r] + bb;
    }
    __syncthreads();

    for (int u = 0; u < 8; ++u) {
        int tk = w * 8 + u;
        float v0 = outT[tk * 256 + l];
        float v1 = outT[tk * 256 + l + 64];
        float v2 = outT[tk * 256 + l + 128];
        float v3 = outT[tk * 256 + l + 192];
        float s = v0 + v1 + v2 + v3, ss = v0 * v0 + v1 * v1 + v2 * v2 + v3 * v3;
        for (int m = 1; m < 64; m <<= 1) { s += __shfl_xor(s, m); ss += __shfl_xor(ss, m); }
        float mean = s * (1.0f / 256.0f);
        float var  = ss * (1.0f / 256.0f) - mean * mean;
        float rs   = rsqrtf(var + 1e-5f);

        size_t gt = tok0 + tk;
        int win = (int)(gt >> 6), n = (int)(gt & 63);
        int b = win >> 6, wh = (win >> 3) & 7, ww = win & 7, i = n >> 3, j = n & 7;
        int pr = (wh * 8 + i + shift) & 63;
        int pc = (ww * 8 + j + shift) & 63;
        float* xp = x + ((size_t)(b * 4096 + pr * 64 + pc)) * 256;
        xp[l]       += (v0 - mean) * rs * n1s[l]       + n1b[l];
        xp[l + 64]  += (v1 - mean) * rs * n1s[l + 64]  + n1b[l + 64];
        xp[l + 128] += (v2 - mean) * rs * n1s[l + 128] + n1b[l + 128];
        xp[l + 192] += (v3 - mean) * rs * n1s[l + 192] + n1b[l + 192];
    }
}

// ---------------- fused MLP (bf16 MFMA): 256 -> 1024 gelu -> 256, post-LN, residual ----------------
__global__ __launch_bounds__(256, 2) void mlp_mfma_kernel(
    float* __restrict__ x, const ushort* __restrict__ w1b, const float* __restrict__ b1,
    const ushort* __restrict__ w2b, const float* __restrict__ b2,
    const float* __restrict__ n2s, const float* __restrict__ n2b)
{
    extern __shared__ ushort smem[];
    ushort* xs  = smem;             // [32][256] bf16, swizzled
    ushort* hid = smem + 32 * 256;  // [32][1024] bf16, swizzled
    float*  outT = (float*)hid;     // [32][256] f32 overlay

    const int t = threadIdx.x;
    const size_t tok0 = (size_t)blockIdx.x * 32;

    {
        int row = t >> 3, seg = t & 7;
        const float4* src = reinterpret_cast<const float4*>(x + (tok0 + row) * 256 + seg * 32);
        #pragma unroll
        for (int c4 = 0; c4 < 8; ++c4) {
            float4 v = src[c4];
            int col = seg * 32 + c4 * 4;
            ushort4 u = { f2b(v.x), f2b(v.y), f2b(v.z), f2b(v.w) };
            *reinterpret_cast<ushort4*>(xs + row * 256 + (col ^ ((row & 7) << 3))) = u;
        }
    }
    __syncthreads();

    const int w = t >> 6, l = t & 63, lr = l & 15, lk = (l >> 4) * 8;
    const int aswz = (lr & 7) << 3;
    const int n0 = w * 256;
    const f32x4 zf = { 0.f, 0.f, 0.f, 0.f };

    {
        f32x4 acc[2][16];
        #pragma unroll
        for (int mf = 0; mf < 2; ++mf)
            #pragma unroll
            for (int nf = 0; nf < 16; ++nf) acc[mf][nf] = zf;

        for (int kt = 0; kt < 8; ++kt) {
            int k0 = kt * 32 + lk;
            bf16x8 a0 = *reinterpret_cast<const bf16x8*>(xs + lr * 256        + (k0 ^ aswz));
            bf16x8 a1 = *reinterpret_cast<const bf16x8*>(xs + (16 + lr) * 256 + (k0 ^ aswz));
            #pragma unroll
            for (int nf = 0; nf < 16; ++nf) {
                bf16x8 b = *reinterpret_cast<const bf16x8*>(w1b + (size_t)(n0 + nf * 16 + lr) * 256 + k0);
                acc[0][nf] = MFMA16(a0, b, acc[0][nf]);
                acc[1][nf] = MFMA16(a1, b, acc[1][nf]);
            }
        }

        #pragma unroll
        for (int nf = 0; nf < 16; ++nf) {
            int hcol = n0 + nf * 16 + lr;
            float bb = b1[hcol];
            #pragma unroll
            for (int mf = 0; mf < 2; ++mf)
                #pragma unroll
                for (int r = 0; r < 4; ++r) {
                    int hrow = mf * 16 + (l >> 4) * 4 + r;
                    float pre = acc[mf][nf][r] + bb;
                    float g = 0.5f * pre * (1.0f + erff(pre * 0.70710678f));
                    hid[hrow * 1024 + (hcol ^ ((hrow & 7) << 3))] = f2b(g);
                }
        }
    }
    __syncthreads();

    f32x4 acc2[2][4];
    #pragma unroll
    for (int mf = 0; mf < 2; ++mf)
        #pragma unroll
        for (int nf = 0; nf < 4; ++nf) acc2[mf][nf] = zf;

    for (int kt = 0; kt < 32; ++kt) {
        int k0 = kt * 32 + lk;
        bf16x8 a0 = *reinterpret_cast<const bf16x8*>(hid + lr * 1024        + (k0 ^ aswz));
        bf16x8 a1 = *reinterpret_cast<const bf16x8*>(hid + (16 + lr) * 1024 + (k0 ^ aswz));
        #pragma unroll
        for (int nf = 0; nf < 4; ++nf) {
            bf16x8 b = *reinterpret_cast<const bf16x8*>(w2b + (size_t)(w * 64 + nf * 16 + lr) * 1024 + k0);
            acc2[0][nf] = MFMA16(a0, b, acc2[0][nf]);
            acc2[1][nf] = MFMA16(a1, b, acc2[1][nf]);
        }
    }
    __syncthreads();

    #pragma unroll
    for (int nf = 0; nf < 4; ++nf) {
        int c = w * 64 + nf * 16 + lr;
        float bb = b2[c];
        #pragma unroll
        for (int mf = 0; mf < 2; ++mf)
            #pragma unroll
            for (int r = 0; r < 4; ++r)
                outT[(mf * 16 + (l >> 4) * 4 + r) * 256 + c] = acc2[mf][nf][r] + bb;
    }
    __syncthreads();

    for (int u = 0; u < 8; ++u) {
        int tk = w * 8 + u;
        float v0 = outT[tk * 256 + l];
        float v1 = outT[tk * 256 + l + 64];
        float v2 = outT[tk * 256 + l + 128];
        float v3 = outT[tk * 256 + l + 192];
        float s = v0 + v1 + v2 + v3, ss = v0 * v0 + v1 * v1 + v2 * v2 + v3 * v3;
        for (int m = 1; m < 64; m <<= 1) { s += __shfl_xor(s, m); ss += __shfl_xor(ss, m); }
        float mean = s * (1.0f / 256.0f);
        float var  = ss * (1.0f / 256.0f) - mean * mean;
        float rs   = rsqrtf(var + 1e-5f);
        float* xp = x + (tok0 + tk) * 256;
        xp[l]       += (v0 - mean) * rs * n2s[l]       + n2b[l];
        xp[l + 64]  += (v1 - mean) * rs * n2s[l + 64]  + n2b[l + 64];
        xp[l + 128] += (v2 - mean) * rs * n2s[l + 128] + n2b[l + 128];
        xp[l + 192] += (v3 - mean) * rs * n2s[l + 192] + n2b[l + 192];
    }
}

// ---------------- launcher ----------------
extern "C" void kernel_launch(void* const* d_in, const int* in_sizes, int n_in,
                              void* d_out, int out_size, void* d_ws, size_t ws_size,
                              hipStream_t stream) {
    (void)in_sizes; (void)n_in; (void)out_size; (void)ws_size;
    const float* tokens = (const float*)d_in[0];
    const float* qkv_w  = (const float*)d_in[3];
    const float* qkv_b  = (const float*)d_in[4];
    const float* lsc    = (const float*)d_in[5];
    const float* cw1    = (const float*)d_in[6];
    const float* cb1    = (const float*)d_in[7];
    const float* cw2    = (const float*)d_in[8];
    const float* pw     = (const float*)d_in[9];
    const float* pb     = (const float*)d_in[10];
    const float* n1s    = (const float*)d_in[11];
    const float* n1b    = (const float*)d_in[12];
    const float* mw1    = (const float*)d_in[13];
    const float* mb1    = (const float*)d_in[14];
    const float* mw2    = (const float*)d_in[15];
    const float* mb2    = (const float*)d_in[16];
    const float* n2s    = (const float*)d_in[17];
    const float* n2b    = (const float*)d_in[18];

    float* x = (float*)d_out;

    // workspace layout (all 16B aligned)
    ushort* attn_out = (ushort*)d_ws;                                  // 32 MB
    float*  biastab  = (float*)((char*)d_ws + (size_t)NTOK * C_ * 2);  // 7200 B
    ushort* pwb      = (ushort*)((char*)biastab + 7200);               // 256 KB
    ushort* w1b      = pwb + 2 * 256 * 256;                            // 1 MB
    ushort* w2b      = w1b + 2 * 1024 * 256;                           // 1 MB
    ushort* qwb      = w2b + 2 * 256 * 1024;                           // 768 KB
    float*  biasx    = (float*)(qwb + 2 * 768 * 256);                  // 128 KB

    f2b_kernel<<<dim3(2 * 256 * 256 / 1024),  dim3(256), 0, stream>>>(pwb, pw);
    f2b_kernel<<<dim3(2 * 1024 * 256 / 1024), dim3(256), 0, stream>>>(w1b, mw1);
    f2b_kernel<<<dim3(2 * 256 * 1024 / 1024), dim3(256), 0, stream>>>(w2b, mw2);
    f2b_kernel<<<dim3(2 * 768 * 256 / 1024),  dim3(256), 0, stream>>>(qwb, qkv_w);

    copy_kernel<<<dim3(NTOK * C_ / 4 / 256), dim3(256), 0, stream>>>(x, tokens);

    for (int l = 0; l < 2; ++l) {
        const int shift = l ? 4 : 0;
        cpb_kernel<<<dim3(225), dim3(256), 0, stream>>>(
            cw1 + (size_t)l * 1024, cb1 + (size_t)l * 512, cw2 + (size_t)l * 4096, biastab);
        biasx_kernel<<<dim3(512), dim3(64), 0, stream>>>(biastab, biasx);
        attn_mfma_kernel<<<dim3(1024), dim3(256), ATTN_LDS, stream>>>(
            x, qwb + (size_t)l * 196608, qkv_b + (size_t)l * 768,
            lsc + (size_t)l * 8, biasx, attn_out, shift);
        proj_mfma_kernel<<<dim3(NTOK / 32), dim3(256), PROJ_LDS, stream>>>(
            attn_out, pwb + (size_t)l * 65536, pb + (size_t)l * 256,
            n1s + (size_t)l * 256, n1b + (size_t)l * 256, x, shift);
        mlp_mfma_kernel<<<dim3(NTOK / 32), dim3(256), MLP_LDS, stream>>>(
            x, w1b + (size_t)l * 262144, mb1 + (size_t)l * 1024,
            w2b + (size_t)l * 262144, mb2 + (size_t)l * 256,
            n2s + (size_t)l * 256, n2b + (size_t)l * 256);
    }
}